// Round 14
// baseline (220.097 us; speedup 1.0000x reference)
//
#include <hip/hip_runtime.h>
#include <stdint.h>

// VQ codebook argmin. N=2048 queries (C=64) vs K=81920 codes.
// out (f32): [quantized_st 131072][vq_loss][commit_loss][idx 2048]
//
// R14 structure (collect pass DELETED):
//  convert: z,emb fp32->bf16 into ws; zero loss/ticket.
//  pass1  : bf16-MFMA dots; store per-(query, 128-code chunk) max (640
//           chunks/query) -- the 16-lane reduce pass1 already did, kept
//           per-slice instead of folded. No atomics, disjoint stores.
//  rescore: per query: qmax = max over its 640 chunkmaxes; chunks with
//           max >= qmax - DMARG survive (winner's chunk provably survives:
//           dot_bf(k*) >= max_bf - (3.9e-6 + 2*eps), eps<=4.2e-6 => bound
//           1.23e-5 < DMARG=1.6e-5). Exact bitwise-numpy rescore of ALL
//           codes in surviving chunks (~3-6 chunks/query) -> winner is
//           unconditionally contained; no CAP/overflow machinery at all.
//           Fused finalize + last-block (fence+ticket) loss write.
#define NQ 2048
#define KK 81920
#define CD 64
#define DMARG 1.6e-5f
#define QPB 64               // queries per q-block (4 groups of 16)
#define NQBLK 32
#define SPX 20               // slices per XCD
#define SPB 5                // slices per block -> 1024 blocks (r12 best)
#define NCHUNK 640           // 128-code chunks per query row

#define OUT_VQ 131072
#define OUT_CM 131073
#define OUT_IDX 131074

// ws layout (bytes); total ~16.0 MB
#define WS_LOSS 0            // float
#define WS_TICKET 256        // uint
#define WS_ZBF  1024         // ushort[131072]  bf16 z     (262144 B)
#define WS_EBF  263168       // ushort[5242880] bf16 emb   (10485760 B)
#define WS_CMAX 10748928     // u32[2048*640] chunk maxima (5242880 B)

typedef short v8s __attribute__((ext_vector_type(8)));
typedef float v4f __attribute__((ext_vector_type(4)));

__device__ __forceinline__ unsigned int f2o(float f) {
  unsigned int u = __float_as_uint(f);
  return (u & 0x80000000u) ? ~u : (u | 0x80000000u);
}
__device__ __forceinline__ float o2f(unsigned int u) {
  unsigned int v = (u & 0x80000000u) ? (u & 0x7FFFFFFFu) : ~u;
  return __uint_as_float(v);
}
__device__ __forceinline__ unsigned int bf16rne(float f) {
  unsigned int u = __float_as_uint(f);
  u = u + 0x7FFFu + ((u >> 16) & 1u);
  return u >> 16;
}

// fp32 -> bf16 for z then emb (grid-stride); zero loss + ticket.
#define NZ4 32768
#define NTOT4 1343488
__global__ __launch_bounds__(256) void convert_kernel(
    const float* __restrict__ z, const float* __restrict__ emb,
    unsigned int* __restrict__ zbf, unsigned int* __restrict__ ebf,
    float* __restrict__ loss, unsigned int* __restrict__ ticket) {
  const int gid = blockIdx.x * 256 + threadIdx.x;
  if (gid == 0) { *loss = 0.0f; *ticket = 0u; }
  const int stride = gridDim.x * 256;
#pragma unroll 1
  for (int i = gid; i < NTOT4; i += stride) {
    const bool isz = (i < NZ4);
    const float4 v = isz ? ((const float4*)z)[i] : ((const float4*)emb)[i - NZ4];
    uint2 o;
    o.x = bf16rne(v.x) | (bf16rne(v.y) << 16);
    o.y = bf16rne(v.z) | (bf16rne(v.w) << 16);
    if (isz) ((uint2*)zbf)[i] = o;
    else     ((uint2*)ebf)[i - NZ4] = o;
  }
}

// Block decode (r12 winner): xcd = bid&7; within an XCD qblk varies fastest.
// Block owns 5 consecutive slices and 64 queries. 1024 blocks.
struct BlkMap { int q0, slice0; };
__device__ __forceinline__ BlkMap decode_block(int bid) {
  BlkMap m;
  const int xcd = bid & 7;
  const int i = bid >> 3;          // 0..127
  const int qblk = i & 31;         // fastest
  const int sgrp = i >> 5;         // 0..3
  m.q0 = qblk * QPB;
  m.slice0 = xcd * SPX + sgrp * SPB;
  return m;
}

// Load 4 code-groups (64 codes) of B-fragments (32 VGPR).
__device__ __forceinline__ void load_B4(v8s (&Bb)[4][2],
                                        const unsigned short* __restrict__ ebf,
                                        int code0, int lrow, int quad) {
#pragma unroll
  for (int cg = 0; cg < 4; ++cg) {
    const unsigned short* er = ebf + (size_t)(code0 + cg * 16 + lrow) * CD + quad * 8;
    Bb[cg][0] = *(const v8s*)er;
    Bb[cg][1] = *(const v8s*)(er + 32);
  }
}

// mfma_f32_16x16x32_bf16 layouts (m89/m91/m120):
//   A: lane holds A[m=lane&15][k=quad*8+j]; B: B[k=quad*8+j][n=lane&15]
//   D: lane,reg r -> D[row=quad*4+r][col=lane&15] (row=query, col=code)
// Wave w owns codes [slice*512 + w*128, +128) per slice; per-slice max is
// reduced over 16 lanes and stored to chunkmax[q][slice*4+wave].
__global__ __launch_bounds__(256, 2) void pass1_kernel(
    const unsigned short* __restrict__ zbf, const unsigned short* __restrict__ ebf,
    unsigned int* __restrict__ cmax) {
  const int tid = threadIdx.x;
  const int wave = tid >> 6, lane = tid & 63;
  const int quad = lane >> 4, lrow = lane & 15;
  const BlkMap bm = decode_block(blockIdx.x);

  v8s A0[4], A1[4];
#pragma unroll
  for (int qg = 0; qg < 4; ++qg) {
    const unsigned short* zr = zbf + (size_t)(bm.q0 + qg * 16 + lrow) * CD + quad * 8;
    A0[qg] = *(const v8s*)zr;
    A1[qg] = *(const v8s*)(zr + 32);
  }

#pragma unroll 1
  for (int s = 0; s < SPB; ++s) {
    float pmax[4][4];
#pragma unroll
    for (int qg = 0; qg < 4; ++qg)
#pragma unroll
      for (int r = 0; r < 4; ++r) pmax[qg][r] = -1e30f;

#pragma unroll 1
    for (int h = 0; h < 2; ++h) {
      v8s B[4][2];
      load_B4(B, ebf, (bm.slice0 + s) * 512 + wave * 128 + h * 64, lrow, quad);
#pragma unroll
      for (int qg = 0; qg < 4; ++qg) {
#pragma unroll
        for (int cg = 0; cg < 4; ++cg) {
          v4f acc = {0.f, 0.f, 0.f, 0.f};
          acc = __builtin_amdgcn_mfma_f32_16x16x32_bf16(A0[qg], B[cg][0], acc, 0, 0, 0);
          acc = __builtin_amdgcn_mfma_f32_16x16x32_bf16(A1[qg], B[cg][1], acc, 0, 0, 0);
#pragma unroll
          for (int r = 0; r < 4; ++r) pmax[qg][r] = fmaxf(pmax[qg][r], acc[r]);
        }
      }
    }

    // 16-lane max reduce (16 independent chains per level)
#pragma unroll
    for (int m = 1; m <= 8; m <<= 1)
#pragma unroll
      for (int qg = 0; qg < 4; ++qg)
#pragma unroll
        for (int r = 0; r < 4; ++r)
          pmax[qg][r] = fmaxf(pmax[qg][r], __shfl_xor(pmax[qg][r], m, 64));

    // store per-(q, chunk) max; chunk = slice*4 + wave; disjoint writers.
    const int ch = (bm.slice0 + s) * 4 + wave;
    if (lrow == 0) {
#pragma unroll
      for (int qg = 0; qg < 4; ++qg)
#pragma unroll
        for (int r = 0; r < 4; ++r)
          cmax[(size_t)(bm.q0 + qg * 16 + quad * 4 + r) * NCHUNK + ch] =
              f2o(pmax[qg][r]);
    }
  }
}

// Exact bitwise-numpy score of code k (round-2/3 verified DAG).
__device__ __forceinline__ unsigned long long exact_key(
    const float* __restrict__ emb, const float zr[CD], float zn2, int k) {
#pragma clang fp contract(off)
  float er[CD];
  const float4* ep = (const float4*)(emb + (size_t)k * CD);
#pragma unroll
  for (int j = 0; j < 16; ++j) {
    float4 v = ep[j];
    er[4 * j] = v.x; er[4 * j + 1] = v.y; er[4 * j + 2] = v.z; er[4 * j + 3] = v.w;
  }
  float acc[16];
#pragma unroll
  for (int j = 0; j < 16; ++j) acc[j] = 0.0f;
#pragma unroll
  for (int q4 = 0; q4 < 16; ++q4) {
    const int jb = 4 * (q4 & 3), cb = 4 * q4;
    acc[jb + 0] = __builtin_fmaf(er[cb + 0], zr[cb + 0], acc[jb + 0]);
    acc[jb + 1] = __builtin_fmaf(er[cb + 1], zr[cb + 1], acc[jb + 1]);
    acc[jb + 2] = __builtin_fmaf(er[cb + 2], zr[cb + 2], acc[jb + 2]);
    acc[jb + 3] = __builtin_fmaf(er[cb + 3], zr[cb + 3], acc[jb + 3]);
  }
  float b8[8], b4[4];
#pragma unroll
  for (int j = 0; j < 8; ++j) b8[j] = acc[j] + acc[j + 8];
#pragma unroll
  for (int j = 0; j < 4; ++j) b4[j] = b8[j] + b8[j + 4];
  const float dot = (b4[0] + b4[2]) + (b4[1] + b4[3]);
  const float t = zn2 - 2.0f * dot;  // single rounding == numpy A - 2B
  return ((unsigned long long)f2o(t) << 32) | (unsigned int)k;
}

// One WAVE per query: scan 640 chunk maxima, survivors = chunks within
// DMARG of the query max; exact-rescore all 128 codes of each survivor
// (2 codes/lane); u64 shuffle-min; finalize. Last block writes losses.
__global__ __launch_bounds__(256) void rescore_finalize_kernel(
    const float* __restrict__ z, const float* __restrict__ emb,
    const unsigned int* __restrict__ cmax, float* __restrict__ out,
    float* __restrict__ loss, unsigned int* __restrict__ ticket) {
#pragma clang fp contract(off)
  const int t = threadIdx.x;
  const int wv = t >> 6, lane = t & 63;
  const int n = blockIdx.x * 4 + wv;

  float zr[CD];
  {
    const float4* zp = (const float4*)(z + (size_t)n * CD);
#pragma unroll
    for (int i = 0; i < 16; ++i) {
      float4 v = zp[i];
      zr[4 * i] = v.x; zr[4 * i + 1] = v.y; zr[4 * i + 2] = v.z; zr[4 * i + 3] = v.w;
    }
  }
  float zn2;
  {
    float r[8];
#pragma unroll
    for (int j = 0; j < 8; ++j) r[j] = zr[j] * zr[j];
#pragma unroll
    for (int i = 8; i < CD; i += 8)
#pragma unroll
      for (int j = 0; j < 8; ++j) r[j] += zr[i + j] * zr[i + j];
    zn2 = ((r[0] + r[1]) + (r[2] + r[3])) + ((r[4] + r[5]) + (r[6] + r[7]));
  }

  // load this query's 640 chunk maxima (10 per lane, coalesced)
  const unsigned int* cm = cmax + (size_t)n * NCHUNK;
  unsigned int val[10];
#pragma unroll
  for (int j = 0; j < 10; ++j) val[j] = cm[j * 64 + lane];
  unsigned int qm = val[0];
#pragma unroll
  for (int j = 1; j < 10; ++j) qm = val[j] > qm ? val[j] : qm;
#pragma unroll
  for (int m = 32; m; m >>= 1) {
    unsigned int o = (unsigned int)__shfl_xor((int)qm, m, 64);
    qm = o > qm ? o : qm;
  }
  const float thr = o2f(qm) - DMARG;

  unsigned long long best = ~0ull;
#pragma unroll 1
  for (int j = 0; j < 10; ++j) {
    unsigned long long mask = __ballot(o2f(val[j]) >= thr);
    while (mask) {
      const int b = __ffsll((long long)mask) - 1;
      mask &= mask - 1;
      const int c0 = (j * 64 + b) * 128;  // surviving chunk's code base
      unsigned long long k1 = exact_key(emb, zr, zn2, c0 + lane);
      unsigned long long k2 = exact_key(emb, zr, zn2, c0 + 64 + lane);
      best = (k1 < best) ? k1 : best;
      best = (k2 < best) ? k2 : best;
    }
  }
#pragma unroll
  for (int m = 32; m; m >>= 1) {
    unsigned long long o = __shfl_xor(best, m, 64);
    best = (o < best) ? o : best;
  }
  const int idx = (int)(best & 0xFFFFFFFFull);

  // finalize: lane = channel. quantized_st = z + (q - z), two f32 roundings.
  const float e = emb[(size_t)idx * CD + lane];
  const float zv = z[(size_t)n * CD + lane];
  const float dst = e - zv;
  out[(size_t)n * CD + lane] = zv + dst;
  if (lane == 0) out[OUT_IDX + n] = (float)idx;
  float d = zv - e;
  float sq = d * d;
#pragma unroll
  for (int off = 32; off > 0; off >>= 1) sq += __shfl_down(sq, off, 64);
  __shared__ float part[4];
  if (lane == 0) part[wv] = sq;
  __syncthreads();
  if (t == 0) {
    atomicAdd(loss, part[0] + part[1] + part[2] + part[3]);
    __threadfence();
    const unsigned int tk = atomicAdd(ticket, 1u);
    if (tk == gridDim.x - 1) {          // last block: all adds visible
      const float m = atomicAdd(loss, 0.0f) / (float)(NQ * CD);
      out[OUT_VQ] = m;
      out[OUT_CM] = m;
    }
  }
}

extern "C" void kernel_launch(void* const* d_in, const int* in_sizes, int n_in,
                              void* d_out, int out_size, void* d_ws, size_t ws_size,
                              hipStream_t stream) {
  const float* z = (const float*)d_in[0];
  const float* emb = (const float*)d_in[1];
  float* out = (float*)d_out;
  char* ws = (char*)d_ws;
  float* loss = (float*)(ws + WS_LOSS);
  unsigned int* ticket = (unsigned int*)(ws + WS_TICKET);
  unsigned int* zbf = (unsigned int*)(ws + WS_ZBF);
  unsigned int* ebf = (unsigned int*)(ws + WS_EBF);
  unsigned int* cmaxp = (unsigned int*)(ws + WS_CMAX);

  convert_kernel<<<1312, 256, 0, stream>>>(z, emb, zbf, ebf, loss, ticket);
  const int nblk = NQBLK * 32;  // 1024 blocks (r12 winner geometry)
  pass1_kernel<<<nblk, 256, 0, stream>>>(
      (const unsigned short*)zbf, (const unsigned short*)ebf, cmaxp);
  rescore_finalize_kernel<<<NQ / 4, 256, 0, stream>>>(z, emb, cmaxp, out, loss, ticket);
}

// Round 15
// 196.468 us; speedup vs baseline: 1.1203x; 1.1203x over previous
//
#include <hip/hip_runtime.h>
#include <stdint.h>

// VQ codebook argmin. N=2048 queries (C=64) vs K=81920 codes.
// out (f32): [quantized_st 131072][vq_loss][commit_loss][idx 2048]
//
// R15 structure (single MFMA pass + filtered rescore):
//  convert: z,emb fp32->bf16 into ws; zero loss/ticket.
//  pass1  : bf16-MFMA dots; store per-(query, 64-code chunk) max
//           (1280 chunks/query). No atomics, disjoint stores.
//  rescore: one block per query. (a) qmax = max over 1280 chunkmaxes;
//           chunks with max >= qmax - DMARG survive (winner's chunk provably
//           survives: dot_bf(k*) >= max_bf - (3.9e-6 + 2*eps), eps<=4.2e-6
//           => bound 1.23e-5 < DMARG=1.6e-5). (b) bf16 VALU re-dot of
//           surviving chunks (exact products, fp32 fma; order error ~1e-9
//           << slack) -> candidate codes with dot >= thr - 1e-7 into LDS
//           list (~6-10/query). (c) exact bitwise-numpy rescore of the
//           candidates only; block-min; fused finalize + ticketed loss.
//           Full-scan fallback if list overflows (p ~ 0).
#define NQ 2048
#define KK 81920
#define CD 64
#define DMARG 1.6e-5f
#define QPB 64               // queries per q-block (4 groups of 16)
#define NQBLK 32
#define SPX 20               // slices per XCD
#define SPB 5                // slices per block -> 1024 blocks (r12 geometry)
#define NCHUNK 1280          // 64-code chunks per query
#define MAXC 192             // candidate list capacity

#define OUT_VQ 131072
#define OUT_CM 131073
#define OUT_IDX 131074

// ws layout (bytes); total ~21.2 MB
#define WS_LOSS 0            // float
#define WS_TICKET 256        // uint
#define WS_ZBF  1024         // ushort[131072]   bf16 z     (262144 B)
#define WS_EBF  263168       // ushort[5242880]  bf16 emb   (10485760 B)
#define WS_CMAX 10748928     // u32[2048*1280] chunk maxima (10485760 B)

typedef short v8s __attribute__((ext_vector_type(8)));
typedef float v4f __attribute__((ext_vector_type(4)));

__device__ __forceinline__ unsigned int f2o(float f) {
  unsigned int u = __float_as_uint(f);
  return (u & 0x80000000u) ? ~u : (u | 0x80000000u);
}
__device__ __forceinline__ float o2f(unsigned int u) {
  unsigned int v = (u & 0x80000000u) ? (u & 0x7FFFFFFFu) : ~u;
  return __uint_as_float(v);
}
__device__ __forceinline__ unsigned int bf16rne(float f) {
  unsigned int u = __float_as_uint(f);
  u = u + 0x7FFFu + ((u >> 16) & 1u);
  return u >> 16;
}
__device__ __forceinline__ float bf2f(short s) {
  return __uint_as_float(((unsigned int)(unsigned short)s) << 16);
}

// fp32 -> bf16 for z then emb (grid-stride); zero loss + ticket.
#define NZ4 32768
#define NTOT4 1343488
__global__ __launch_bounds__(256) void convert_kernel(
    const float* __restrict__ z, const float* __restrict__ emb,
    unsigned int* __restrict__ zbf, unsigned int* __restrict__ ebf,
    float* __restrict__ loss, unsigned int* __restrict__ ticket) {
  const int gid = blockIdx.x * 256 + threadIdx.x;
  if (gid == 0) { *loss = 0.0f; *ticket = 0u; }
  const int stride = gridDim.x * 256;
#pragma unroll 1
  for (int i = gid; i < NTOT4; i += stride) {
    const bool isz = (i < NZ4);
    const float4 v = isz ? ((const float4*)z)[i] : ((const float4*)emb)[i - NZ4];
    uint2 o;
    o.x = bf16rne(v.x) | (bf16rne(v.y) << 16);
    o.y = bf16rne(v.z) | (bf16rne(v.w) << 16);
    if (isz) ((uint2*)zbf)[i] = o;
    else     ((uint2*)ebf)[i - NZ4] = o;
  }
}

// Block decode (r12 winner): xcd = bid&7; within an XCD qblk varies fastest.
struct BlkMap { int q0, slice0; };
__device__ __forceinline__ BlkMap decode_block(int bid) {
  BlkMap m;
  const int xcd = bid & 7;
  const int i = bid >> 3;          // 0..127
  const int qblk = i & 31;         // fastest
  const int sgrp = i >> 5;         // 0..3
  m.q0 = qblk * QPB;
  m.slice0 = xcd * SPX + sgrp * SPB;
  return m;
}

// Load 4 code-groups (64 codes) of B-fragments (32 VGPR).
__device__ __forceinline__ void load_B4(v8s (&Bb)[4][2],
                                        const unsigned short* __restrict__ ebf,
                                        int code0, int lrow, int quad) {
#pragma unroll
  for (int cg = 0; cg < 4; ++cg) {
    const unsigned short* er = ebf + (size_t)(code0 + cg * 16 + lrow) * CD + quad * 8;
    Bb[cg][0] = *(const v8s*)er;
    Bb[cg][1] = *(const v8s*)(er + 32);
  }
}

// mfma_f32_16x16x32_bf16 layouts (m89/m91/m120):
//   A: lane holds A[m=lane&15][k=quad*8+j]; B: B[k=quad*8+j][n=lane&15]
//   D: lane,reg r -> D[row=quad*4+r][col=lane&15] (row=query, col=code)
// Wave w owns codes [slice*512 + w*128, +128); per h-half (64 codes) the
// 16-lane max is reduced and stored to cmax[q][slice*8 + wave*2 + h].
__global__ __launch_bounds__(256, 2) void pass1_kernel(
    const unsigned short* __restrict__ zbf, const unsigned short* __restrict__ ebf,
    unsigned int* __restrict__ cmax) {
  const int tid = threadIdx.x;
  const int wave = tid >> 6, lane = tid & 63;
  const int quad = lane >> 4, lrow = lane & 15;
  const BlkMap bm = decode_block(blockIdx.x);

  v8s A0[4], A1[4];
#pragma unroll
  for (int qg = 0; qg < 4; ++qg) {
    const unsigned short* zr = zbf + (size_t)(bm.q0 + qg * 16 + lrow) * CD + quad * 8;
    A0[qg] = *(const v8s*)zr;
    A1[qg] = *(const v8s*)(zr + 32);
  }

#pragma unroll 1
  for (int s = 0; s < SPB; ++s) {
#pragma unroll 1
    for (int h = 0; h < 2; ++h) {
      float pmax[4][4];
#pragma unroll
      for (int qg = 0; qg < 4; ++qg)
#pragma unroll
        for (int r = 0; r < 4; ++r) pmax[qg][r] = -1e30f;

      v8s B[4][2];
      load_B4(B, ebf, (bm.slice0 + s) * 512 + wave * 128 + h * 64, lrow, quad);
#pragma unroll
      for (int qg = 0; qg < 4; ++qg) {
#pragma unroll
        for (int cg = 0; cg < 4; ++cg) {
          v4f acc = {0.f, 0.f, 0.f, 0.f};
          acc = __builtin_amdgcn_mfma_f32_16x16x32_bf16(A0[qg], B[cg][0], acc, 0, 0, 0);
          acc = __builtin_amdgcn_mfma_f32_16x16x32_bf16(A1[qg], B[cg][1], acc, 0, 0, 0);
#pragma unroll
          for (int r = 0; r < 4; ++r) pmax[qg][r] = fmaxf(pmax[qg][r], acc[r]);
        }
      }

      // 16-lane max reduce (16 independent chains per level)
#pragma unroll
      for (int m = 1; m <= 8; m <<= 1)
#pragma unroll
        for (int qg = 0; qg < 4; ++qg)
#pragma unroll
          for (int r = 0; r < 4; ++r)
            pmax[qg][r] = fmaxf(pmax[qg][r], __shfl_xor(pmax[qg][r], m, 64));

      // chunk id = slice*8 + wave*2 + h; codes [chunk*64, +64). Disjoint.
      const int ch = (bm.slice0 + s) * 8 + wave * 2 + h;
      if (lrow == 0) {
#pragma unroll
        for (int qg = 0; qg < 4; ++qg)
#pragma unroll
          for (int r = 0; r < 4; ++r)
            cmax[(size_t)(bm.q0 + qg * 16 + quad * 4 + r) * NCHUNK + ch] =
                f2o(pmax[qg][r]);
      }
    }
  }
}

// Exact bitwise-numpy score of code k (round-2/3 verified DAG).
__device__ __forceinline__ unsigned long long exact_key(
    const float* __restrict__ emb, const float zr[CD], float zn2, int k) {
#pragma clang fp contract(off)
  float er[CD];
  const float4* ep = (const float4*)(emb + (size_t)k * CD);
#pragma unroll
  for (int j = 0; j < 16; ++j) {
    float4 v = ep[j];
    er[4 * j] = v.x; er[4 * j + 1] = v.y; er[4 * j + 2] = v.z; er[4 * j + 3] = v.w;
  }
  float acc[16];
#pragma unroll
  for (int j = 0; j < 16; ++j) acc[j] = 0.0f;
#pragma unroll
  for (int q4 = 0; q4 < 16; ++q4) {
    const int jb = 4 * (q4 & 3), cb = 4 * q4;
    acc[jb + 0] = __builtin_fmaf(er[cb + 0], zr[cb + 0], acc[jb + 0]);
    acc[jb + 1] = __builtin_fmaf(er[cb + 1], zr[cb + 1], acc[jb + 1]);
    acc[jb + 2] = __builtin_fmaf(er[cb + 2], zr[cb + 2], acc[jb + 2]);
    acc[jb + 3] = __builtin_fmaf(er[cb + 3], zr[cb + 3], acc[jb + 3]);
  }
  float b8[8], b4[4];
#pragma unroll
  for (int j = 0; j < 8; ++j) b8[j] = acc[j] + acc[j + 8];
#pragma unroll
  for (int j = 0; j < 4; ++j) b4[j] = b8[j] + b8[j + 4];
  const float dot = (b4[0] + b4[2]) + (b4[1] + b4[3]);
  const float t = zn2 - 2.0f * dot;  // single rounding == numpy A - 2B
  return ((unsigned long long)f2o(t) << 32) | (unsigned int)k;
}

// One BLOCK per query (2048 blocks).
__global__ __launch_bounds__(256) void rescore_finalize_kernel(
    const float* __restrict__ z, const float* __restrict__ emb,
    const unsigned short* __restrict__ zbf, const unsigned short* __restrict__ ebf,
    const unsigned int* __restrict__ cmax, float* __restrict__ out,
    float* __restrict__ loss, unsigned int* __restrict__ ticket) {
#pragma clang fp contract(off)
  const int tid = threadIdx.x;
  const int wv = tid >> 6, lane = tid & 63;
  const int n = blockIdx.x;

  __shared__ unsigned int smax[4];
  __shared__ int lcnt;
  __shared__ int list[MAXC];
  __shared__ unsigned long long bkey[4];
  if (tid == 0) lcnt = 0;

  // phase (a): qmax over 1280 chunk maxima (5 per thread, coalesced)
  const unsigned int* cm = cmax + (size_t)n * NCHUNK;
  unsigned int val[5];
#pragma unroll
  for (int j = 0; j < 5; ++j) val[j] = cm[j * 256 + tid];
  unsigned int qm = val[0];
#pragma unroll
  for (int j = 1; j < 5; ++j) qm = val[j] > qm ? val[j] : qm;
#pragma unroll
  for (int m = 32; m; m >>= 1) {
    unsigned int o = (unsigned int)__shfl_xor((int)qm, m, 64);
    qm = o > qm ? o : qm;
  }
  if (lane == 0) smax[wv] = qm;
  __syncthreads();
  {
    unsigned int a = smax[0] > smax[1] ? smax[0] : smax[1];
    unsigned int b = smax[2] > smax[3] ? smax[2] : smax[3];
    qm = a > b ? a : b;
  }
  const float thr = o2f(qm) - DMARG;
  const float thrc = thr - 1e-7f;  // slack for VALU-vs-MFMA summation order

  // z row in bf16 as fp32 (must match MFMA's A operand values exactly)
  float zb[CD];
  {
    const v8s* zp = (const v8s*)(zbf + (size_t)n * CD);
#pragma unroll
    for (int i = 0; i < 8; ++i) {
      v8s v = zp[i];
#pragma unroll
      for (int e = 0; e < 8; ++e) zb[i * 8 + e] = bf2f(v[e]);
    }
  }

  // phase (b): survivors -> bf16 re-dot -> candidate list
#pragma unroll 1
  for (int j = 0; j < 5; ++j) {
    unsigned long long mask = __ballot(o2f(val[j]) >= thr);
    while (mask) {
      const int b = __ffsll((long long)mask) - 1;
      mask &= mask - 1;
      const int chunk = j * 256 + wv * 64 + b;
      const int code = chunk * 64 + lane;  // one code per lane
      const v8s* er = (const v8s*)(ebf + (size_t)code * CD);
      float dot = 0.0f;
#pragma unroll
      for (int i = 0; i < 8; ++i) {
        v8s v = er[i];
#pragma unroll
        for (int e = 0; e < 8; ++e)
          dot = __builtin_fmaf(bf2f(v[e]), zb[i * 8 + e], dot);
      }
      if (dot >= thrc) {
        const int pos = atomicAdd(&lcnt, 1);
        if (pos < MAXC) list[pos] = code;
      }
    }
  }
  __syncthreads();
  const int nc = lcnt;

  // phase (c): exact rescore of candidates (verbatim bitwise-numpy DAG)
  float zr[CD];
  {
    const float4* zp = (const float4*)(z + (size_t)n * CD);
#pragma unroll
    for (int i = 0; i < 16; ++i) {
      float4 v = zp[i];
      zr[4 * i] = v.x; zr[4 * i + 1] = v.y; zr[4 * i + 2] = v.z; zr[4 * i + 3] = v.w;
    }
  }
  float zn2;
  {
    float r[8];
#pragma unroll
    for (int j = 0; j < 8; ++j) r[j] = zr[j] * zr[j];
#pragma unroll
    for (int i = 8; i < CD; i += 8)
#pragma unroll
      for (int j = 0; j < 8; ++j) r[j] += zr[i + j] * zr[i + j];
    zn2 = ((r[0] + r[1]) + (r[2] + r[3])) + ((r[4] + r[5]) + (r[6] + r[7]));
  }

  unsigned long long best = ~0ull;
  if (nc <= MAXC) {
    if (tid < nc) best = exact_key(emb, zr, zn2, list[tid]);
  } else {  // overflow fallback: exact full scan (p ~ 0)
#pragma unroll 1
    for (int k = tid; k < KK; k += 256) {
      unsigned long long key = exact_key(emb, zr, zn2, k);
      best = (key < best) ? key : best;
    }
  }
#pragma unroll
  for (int m = 32; m; m >>= 1) {
    unsigned long long o = __shfl_xor(best, m, 64);
    best = (o < best) ? o : best;
  }
  if (lane == 0) bkey[wv] = best;
  __syncthreads();
  if (tid == 0) {
    unsigned long long a = bkey[0] < bkey[1] ? bkey[0] : bkey[1];
    unsigned long long b = bkey[2] < bkey[3] ? bkey[2] : bkey[3];
    bkey[0] = a < b ? a : b;
  }
  __syncthreads();
  const int idx = (int)(bkey[0] & 0xFFFFFFFFull);

  // finalize (wave 0): lane = channel; quantized_st = z + (q - z).
  if (tid < 64) {
    const float e = emb[(size_t)idx * CD + tid];
    const float zv = z[(size_t)n * CD + tid];
    const float dst = e - zv;
    out[(size_t)n * CD + tid] = zv + dst;
    if (tid == 0) out[OUT_IDX + n] = (float)idx;
    float d = zv - e;
    float sq = d * d;
#pragma unroll
    for (int off = 32; off > 0; off >>= 1) sq += __shfl_down(sq, off, 64);
    if (tid == 0) {
      atomicAdd(loss, sq);
      __threadfence();
      const unsigned int tk = atomicAdd(ticket, 1u);
      if (tk == gridDim.x - 1) {
        const float m = atomicAdd(loss, 0.0f) / (float)(NQ * CD);
        out[OUT_VQ] = m;
        out[OUT_CM] = m;
      }
    }
  }
}

extern "C" void kernel_launch(void* const* d_in, const int* in_sizes, int n_in,
                              void* d_out, int out_size, void* d_ws, size_t ws_size,
                              hipStream_t stream) {
  const float* z = (const float*)d_in[0];
  const float* emb = (const float*)d_in[1];
  float* out = (float*)d_out;
  char* ws = (char*)d_ws;
  float* loss = (float*)(ws + WS_LOSS);
  unsigned int* ticket = (unsigned int*)(ws + WS_TICKET);
  unsigned int* zbf = (unsigned int*)(ws + WS_ZBF);
  unsigned int* ebf = (unsigned int*)(ws + WS_EBF);
  unsigned int* cmaxp = (unsigned int*)(ws + WS_CMAX);

  convert_kernel<<<1312, 256, 0, stream>>>(z, emb, zbf, ebf, loss, ticket);
  pass1_kernel<<<1024, 256, 0, stream>>>(
      (const unsigned short*)zbf, (const unsigned short*)ebf, cmaxp);
  rescore_finalize_kernel<<<NQ, 256, 0, stream>>>(
      z, emb, (const unsigned short*)zbf, (const unsigned short*)ebf,
      cmaxp, out, loss, ticket);
}